// Round 1
// baseline (897.631 us; speedup 1.0000x reference)
//
#include <hip/hip_runtime.h>

#define KNN 20
#define EPSBN 1e-5f

__device__ __forceinline__ float lrelu(float z) { return fmaxf(z, 0.2f * z); }

// Full-wave (64-lane) float sum via DPP (VALU pipe, no LDS). Result broadcast to all lanes.
__device__ __forceinline__ float wave64_sum(float x) {
#define DPP_ADD(ctrl)                                                                   \
  {                                                                                     \
    int _t = __builtin_amdgcn_update_dpp(0, __float_as_int(x), (ctrl), 0xF, 0xF, true); \
    x += __int_as_float(_t);                                                            \
  }
  DPP_ADD(0x111)  // row_shr:1
  DPP_ADD(0x112)  // row_shr:2
  DPP_ADD(0x114)  // row_shr:4
  DPP_ADD(0x118)  // row_shr:8  -> lane 15 of each row16 has row sum
  DPP_ADD(0x142)  // row_bcast15 -> lane31 = rows0+1, lane63 = rows2+3
  DPP_ADD(0x143)  // row_bcast31 -> lane63 = total
#undef DPP_ADD
  return __int_as_float(__builtin_amdgcn_readlane(__float_as_int(x), 63));
}

// ---------------- K1: kNN top-20 (thread per point, x[b] in LDS) ----------------
__global__ __launch_bounds__(256) void knn_kernel(const float* __restrict__ x,
                                                  int* __restrict__ idx_out,
                                                  float4* __restrict__ xq_out) {
  __shared__ float4 xl[1024];        // 16 KB: (x,y,z,||x||^2)
  __shared__ float vals[KNN][256];   // 20 KB
  __shared__ int   inds[KNN][256];   // 20 KB
  const int b   = blockIdx.x >> 2;
  const int i0  = (blockIdx.x & 3) << 8;
  const int tid = threadIdx.x;
  const float* xb = x + b * 3072;
#pragma unroll
  for (int r = 0; r < 4; ++r) {
    const int j = tid + (r << 8);
    const float x0 = xb[j], x1 = xb[1024 + j], x2 = xb[2048 + j];
    float4 p;
    p.x = x0; p.y = x1; p.z = x2;
    p.w = x0 * x0 + x1 * x1 + x2 * x2;
    xl[j] = p;
    if ((blockIdx.x & 3) == 0) xq_out[(b << 10) + j] = p;  // write packed pts once per b
  }
#pragma unroll
  for (int k = 0; k < KNN; ++k) vals[k][tid] = -INFINITY;
  __syncthreads();

  const int i = i0 + tid;
  const float4 ci = xl[i];
  const float xxi = ci.w;
  float vmin = -INFINITY;
  for (int j = 0; j < 1024; ++j) {
    const float4 p = xl[j];                                  // broadcast read
    const float dot = ci.x * p.x + ci.y * p.y + ci.z * p.z;
    const float pd = 2.0f * dot - xxi - p.w;                 // = -||xi-xj||^2
    if (pd > vmin) {                                         // strict > keeps lower index on ties
      int q = KNN - 1;
      while (q > 0 && pd > vals[q - 1][tid]) {
        vals[q][tid] = vals[q - 1][tid];
        inds[q][tid] = inds[q - 1][tid];
        --q;
      }
      vals[q][tid] = pd;
      inds[q][tid] = j;
      vmin = vals[KNN - 1][tid];
    }
  }
  int* op = idx_out + ((b << 10) + i) * KNN;
#pragma unroll
  for (int k = 0; k < KNN; ++k) op[k] = inds[k][tid];
}

// ---------------- K2: LAB attention (one wave per point, lane = channel) ----------------
__global__ __launch_bounds__(256) void lab_kernel(const float4* __restrict__ xq,
                                                  const int* __restrict__ idx,
                                                  const float* __restrict__ Wk,
                                                  const float* __restrict__ Wv,
                                                  const float* __restrict__ Ws,
                                                  const float* __restrict__ bnk,
                                                  const float* __restrict__ bnv,
                                                  const float* __restrict__ bns,
                                                  float* __restrict__ agg_out) {
  const int lane = threadIdx.x & 63;
  int point = (blockIdx.x << 2) + (threadIdx.x >> 6);
  point = __builtin_amdgcn_readfirstlane(point);  // wave-uniform -> scalar loads
  const int b = point >> 10;
  const int c = lane;

  // Fold eval-mode BN into weights: bn(z) = z*scale + shift
  const float sk = bnk[c] / sqrtf(bnk[192 + c] + EPSBN);
  const float hk = bnk[64 + c] - bnk[128 + c] * sk;
  const float sv = bnv[c] / sqrtf(bnv[192 + c] + EPSBN);
  const float hv = bnv[64 + c] - bnv[128 + c] * sv;
  const float ss = bns[0] / sqrtf(bns[3] + EPSBN);
  const float hs = bns[1] - bns[2] * ss;

  float wv[10];
#pragma unroll
  for (int f = 0; f < 10; ++f) wv[f] = Wv[c * 10 + f] * sv;
  const float wss = Ws[c] * ss;
  const float wk0 = Wk[c * 3 + 0] * sk, wk1 = Wk[c * 3 + 1] * sk, wk2 = Wk[c * 3 + 2] * sk;

  const float4 ctr = xq[point];
  const float q = lrelu(wk0 * ctr.x + wk1 * ctr.y + wk2 * ctr.z + hk);

  const int* ip = idx + point * KNN;
  float v[KNN], s[KNN];
#pragma unroll
  for (int k = 0; k < KNN; ++k) {
    const int j = ip[k];
    const float4 nb = xq[(b << 10) + j];
    const float d0 = nb.x - ctr.x, d1 = nb.y - ctr.y, d2 = nb.z - ctr.z;
    const float ded = d0 * d0 + d1 * d1 + d2 * d2;
    const float z = wv[0] * ded + wv[1] * d0 + wv[2] * d1 + wv[3] * d2 + wv[4] * ctr.x +
                    wv[5] * ctr.y + wv[6] * ctr.z + wv[7] * nb.x + wv[8] * nb.y +
                    wv[9] * nb.z + hv;
    const float vk = lrelu(z);
    v[k] = vk;
    s[k] = lrelu(wave64_sum(wss * (q + vk)) + hs);  // Sigma_c Ws_c*(q+v), BN folded
  }
  // softmax over k (wave-uniform values)
  float m = s[0];
#pragma unroll
  for (int k = 1; k < KNN; ++k) m = fmaxf(m, s[k]);
  float e[KNN];
  float den = 0.f;
#pragma unroll
  for (int k = 0; k < KNN; ++k) {
    e[k] = __expf(s[k] - m);
    den += e[k];
  }
  const float inv = 1.0f / den;
  float agg = 0.f;
#pragma unroll
  for (int k = 0; k < KNN; ++k) agg = fmaf(v[k], e[k] * inv, agg);
  agg_out[(point << 6) + c] = agg;  // [point][c] -> coalesced
}

// ---------------- K3: conv2 (64x64) + BN + ReLU (thread per point, W2 via SMEM) ----------------
__global__ __launch_bounds__(256) void conv2_kernel(const float* __restrict__ agg,
                                                    const float* __restrict__ W2,
                                                    const float* __restrict__ b2,
                                                    const float* __restrict__ bnc2,
                                                    float* __restrict__ out) {
  const int t = blockIdx.x * 256 + threadIdx.x;  // t = b*1024 + n
  const float4* a4 = (const float4*)(agg + (t << 6));
  float acc[64];
#pragma unroll
  for (int o = 0; o < 64; ++o) acc[o] = 0.f;
#pragma unroll
  for (int cq = 0; cq < 16; ++cq) {
    const float4 a = a4[cq];
#pragma unroll
    for (int o = 0; o < 64; ++o) {
      const float* w = W2 + (o << 6) + (cq << 2);  // threadIdx-independent -> s_load
      acc[o] = fmaf(w[0], a.x, fmaf(w[1], a.y, fmaf(w[2], a.z, fmaf(w[3], a.w, acc[o]))));
    }
  }
  const int b = t >> 10, n = t & 1023;
  float* op = out + (b << 16) + n;
#pragma unroll
  for (int o = 0; o < 64; ++o) {
    const float sc = bnc2[o] / sqrtf(bnc2[192 + o] + EPSBN);
    const float z = acc[o] + b2[o];
    op[o << 10] = fmaxf(fmaf(z - bnc2[128 + o], sc, bnc2[64 + o]), 0.f);
  }
}

extern "C" void kernel_launch(void* const* d_in, const int* in_sizes, int n_in,
                              void* d_out, int out_size, void* d_ws, size_t ws_size,
                              hipStream_t stream) {
  const float* x    = (const float*)d_in[0];
  const float* Wk   = (const float*)d_in[1];
  const float* Wv   = (const float*)d_in[2];
  const float* Ws   = (const float*)d_in[3];
  const float* W2   = (const float*)d_in[4];
  const float* b2   = (const float*)d_in[5];
  const float* bnk  = (const float*)d_in[6];
  const float* bnv  = (const float*)d_in[7];
  const float* bns  = (const float*)d_in[8];
  const float* bnc2 = (const float*)d_in[9];

  // ws layout: xq (1 MB) | idx (5 MB) | agg (16 MB)  => needs ~22 MB
  float4* xq = (float4*)d_ws;
  int* idx   = (int*)((char*)d_ws + (1 << 20));
  float* agg = (float*)((char*)d_ws + 6291456);
  float* out = (float*)d_out;

  knn_kernel<<<256, 256, 0, stream>>>(x, idx, xq);
  lab_kernel<<<16384, 256, 0, stream>>>(xq, idx, Wk, Wv, Ws, bnk, bnv, bns, agg);
  conv2_kernel<<<256, 256, 0, stream>>>(agg, W2, b2, bnc2, out);
}

// Round 2
// 260.091 us; speedup vs baseline: 3.4512x; 3.4512x over previous
//
#include <hip/hip_runtime.h>

#define KNN 20
#define EPSBN 1e-5f

__device__ __forceinline__ float lrelu(float z) { return fmaxf(z, 0.2f * z); }

// Full-wave (64-lane) float sum via DPP (VALU pipe, no LDS). Result broadcast to all lanes.
__device__ __forceinline__ float wave64_sum(float x) {
#define DPP_ADD(ctrl)                                                                   \
  {                                                                                     \
    int _t = __builtin_amdgcn_update_dpp(0, __float_as_int(x), (ctrl), 0xF, 0xF, true); \
    x += __int_as_float(_t);                                                            \
  }
  DPP_ADD(0x111)  // row_shr:1
  DPP_ADD(0x112)  // row_shr:2
  DPP_ADD(0x114)  // row_shr:4
  DPP_ADD(0x118)  // row_shr:8
  DPP_ADD(0x142)  // row_bcast15
  DPP_ADD(0x143)  // row_bcast31 -> lane63 = total
#undef DPP_ADD
  return __int_as_float(__builtin_amdgcn_readlane(__float_as_int(x), 63));
}

// Full-wave float max, broadcast to all lanes. bound_ctrl=false + old=self so
// invalid source lanes contribute max(x,x)=x (0-fill would corrupt pd<=0 maxima).
__device__ __forceinline__ float wave64_max(float x) {
#define DPP_MAX(ctrl)                                                                    \
  {                                                                                      \
    int _xb = __float_as_int(x);                                                         \
    int _t = __builtin_amdgcn_update_dpp(_xb, _xb, (ctrl), 0xF, 0xF, false);             \
    x = fmaxf(x, __int_as_float(_t));                                                    \
  }
  DPP_MAX(0x111) DPP_MAX(0x112) DPP_MAX(0x114) DPP_MAX(0x118)
  DPP_MAX(0x142) DPP_MAX(0x143)
#undef DPP_MAX
  return __int_as_float(__builtin_amdgcn_readlane(__float_as_int(x), 63));
}

// ---------------- K0: pack points as (x,y,z,||x||^2) ----------------
__global__ __launch_bounds__(256) void prep_kernel(const float* __restrict__ x,
                                                   float4* __restrict__ xq) {
  const int t = blockIdx.x * 256 + threadIdx.x;  // t = b*1024 + n
  const int b = t >> 10, n = t & 1023;
  const float* xb = x + b * 3072;
  const float x0 = xb[n], x1 = xb[1024 + n], x2 = xb[2048 + n];
  float4 p;
  p.x = x0; p.y = x1; p.z = x2;
  p.w = x0 * x0 + x1 * x1 + x2 * x2;
  xq[t] = p;
}

// ---------------- K1: kNN top-20 SET (one wave per point, register-only) ----------------
// softmax+weighted-sum downstream is permutation-invariant in k, so only the
// top-20 set is needed, not top_k's ordering.
__global__ __launch_bounds__(256) void knn_kernel(const float4* __restrict__ xq,
                                                  int* __restrict__ idx_out) {
  const int lane = threadIdx.x & 63;
  const int point = blockIdx.x * 4 + (threadIdx.x >> 6);
  const int b = point >> 10;
  const float4* xb = xq + (b << 10);
  const float4 ci = xq[point];

  float val[16];
  int idx[16];
#pragma unroll
  for (int r = 0; r < 16; ++r) {
    const int j = (r << 6) + lane;              // coalesced dwordx4 across lanes
    const float4 p = xb[j];
    const float dot = ci.x * p.x + ci.y * p.y + ci.z * p.z;
    val[r] = 2.0f * dot - ci.w - p.w;           // = -||xi-xj||^2 (same formula as R1)
    idx[r] = j;
  }

  // Per-lane bitonic sort, descending by val (indices follow). Fully unrolled
  // -> static register indexing, branch-free.
#pragma unroll
  for (int kk = 2; kk <= 16; kk <<= 1) {
#pragma unroll
    for (int jj = kk >> 1; jj > 0; jj >>= 1) {
#pragma unroll
      for (int i = 0; i < 16; ++i) {
        const int l = i ^ jj;
        if (l > i) {
          const bool up = ((i & kk) == 0);
          const bool sw = up ? (val[i] < val[l]) : (val[i] > val[l]);
          const float tv = val[i];
          const int ti = idx[i];
          val[i] = sw ? val[l] : val[i];
          idx[i] = sw ? idx[l] : idx[i];
          val[l] = sw ? tv : val[l];
          idx[l] = sw ? ti : idx[l];
        }
      }
    }
  }

  // 20 extraction rounds: wave-max of list heads, winner pops (register shift).
  int outidx = 0;  // lane r collects rank-r index
#pragma unroll
  for (int r = 0; r < KNN; ++r) {
    const float wm = wave64_max(val[0]);
    const unsigned long long ball = __ballot(val[0] == wm);
    const int first = (int)__ffsll(ball) - 1;
    const int widx = __builtin_amdgcn_readlane(idx[0], first);
    if (lane == r) outidx = widx;
    if (lane == first) {
#pragma unroll
      for (int t = 0; t < 15; ++t) {
        val[t] = val[t + 1];
        idx[t] = idx[t + 1];
      }
      val[15] = -INFINITY;
    }
  }
  if (lane < KNN) idx_out[point * KNN + lane] = outidx;  // coalesced
}

// ---------------- K2: LAB attention (one wave per point, lane = channel) ----------------
__global__ __launch_bounds__(256) void lab_kernel(const float4* __restrict__ xq,
                                                  const int* __restrict__ idx,
                                                  const float* __restrict__ Wk,
                                                  const float* __restrict__ Wv,
                                                  const float* __restrict__ Ws,
                                                  const float* __restrict__ bnk,
                                                  const float* __restrict__ bnv,
                                                  const float* __restrict__ bns,
                                                  float* __restrict__ agg_out) {
  const int lane = threadIdx.x & 63;
  int point = (blockIdx.x << 2) + (threadIdx.x >> 6);
  point = __builtin_amdgcn_readfirstlane(point);  // wave-uniform -> scalar loads
  const int b = point >> 10;
  const int c = lane;

  // Fold eval-mode BN into weights: bn(z) = z*scale + shift
  const float sk = bnk[c] / sqrtf(bnk[192 + c] + EPSBN);
  const float hk = bnk[64 + c] - bnk[128 + c] * sk;
  const float sv = bnv[c] / sqrtf(bnv[192 + c] + EPSBN);
  const float hv = bnv[64 + c] - bnv[128 + c] * sv;
  const float ss = bns[0] / sqrtf(bns[3] + EPSBN);
  const float hs = bns[1] - bns[2] * ss;

  float wv[10];
#pragma unroll
  for (int f = 0; f < 10; ++f) wv[f] = Wv[c * 10 + f] * sv;
  const float wss = Ws[c] * ss;
  const float wk0 = Wk[c * 3 + 0] * sk, wk1 = Wk[c * 3 + 1] * sk, wk2 = Wk[c * 3 + 2] * sk;

  const float4 ctr = xq[point];
  const float q = lrelu(wk0 * ctr.x + wk1 * ctr.y + wk2 * ctr.z + hk);

  const int* ip = idx + point * KNN;
  float v[KNN], s[KNN];
#pragma unroll
  for (int k = 0; k < KNN; ++k) {
    const int j = ip[k];
    const float4 nb = xq[(b << 10) + j];
    const float d0 = nb.x - ctr.x, d1 = nb.y - ctr.y, d2 = nb.z - ctr.z;
    const float ded = d0 * d0 + d1 * d1 + d2 * d2;
    const float z = wv[0] * ded + wv[1] * d0 + wv[2] * d1 + wv[3] * d2 + wv[4] * ctr.x +
                    wv[5] * ctr.y + wv[6] * ctr.z + wv[7] * nb.x + wv[8] * nb.y +
                    wv[9] * nb.z + hv;
    const float vk = lrelu(z);
    v[k] = vk;
    s[k] = lrelu(wave64_sum(wss * (q + vk)) + hs);  // Sigma_c Ws_c*(q+v), BN folded
  }
  // softmax over k (wave-uniform values)
  float m = s[0];
#pragma unroll
  for (int k = 1; k < KNN; ++k) m = fmaxf(m, s[k]);
  float e[KNN];
  float den = 0.f;
#pragma unroll
  for (int k = 0; k < KNN; ++k) {
    e[k] = __expf(s[k] - m);
    den += e[k];
  }
  const float inv = 1.0f / den;
  float agg = 0.f;
#pragma unroll
  for (int k = 0; k < KNN; ++k) agg = fmaf(v[k], e[k] * inv, agg);
  agg_out[(point << 6) + c] = agg;  // [point][c] -> coalesced
}

// ---------------- K3: conv2 (64x64) + BN + ReLU (thread per point, W2 via SMEM) ----------------
__global__ __launch_bounds__(256) void conv2_kernel(const float* __restrict__ agg,
                                                    const float* __restrict__ W2,
                                                    const float* __restrict__ b2,
                                                    const float* __restrict__ bnc2,
                                                    float* __restrict__ out) {
  const int t = blockIdx.x * 256 + threadIdx.x;  // t = b*1024 + n
  const float4* a4 = (const float4*)(agg + (t << 6));
  float acc[64];
#pragma unroll
  for (int o = 0; o < 64; ++o) acc[o] = 0.f;
#pragma unroll
  for (int cq = 0; cq < 16; ++cq) {
    const float4 a = a4[cq];
#pragma unroll
    for (int o = 0; o < 64; ++o) {
      const float* w = W2 + (o << 6) + (cq << 2);  // threadIdx-independent -> s_load
      acc[o] = fmaf(w[0], a.x, fmaf(w[1], a.y, fmaf(w[2], a.z, fmaf(w[3], a.w, acc[o]))));
    }
  }
  const int b = t >> 10, n = t & 1023;
  float* op = out + (b << 16) + n;
#pragma unroll
  for (int o = 0; o < 64; ++o) {
    const float sc = bnc2[o] / sqrtf(bnc2[192 + o] + EPSBN);
    const float z = acc[o] + b2[o];
    op[o << 10] = fmaxf(fmaf(z - bnc2[128 + o], sc, bnc2[64 + o]), 0.f);
  }
}

extern "C" void kernel_launch(void* const* d_in, const int* in_sizes, int n_in,
                              void* d_out, int out_size, void* d_ws, size_t ws_size,
                              hipStream_t stream) {
  const float* x    = (const float*)d_in[0];
  const float* Wk   = (const float*)d_in[1];
  const float* Wv   = (const float*)d_in[2];
  const float* Ws   = (const float*)d_in[3];
  const float* W2   = (const float*)d_in[4];
  const float* b2   = (const float*)d_in[5];
  const float* bnk  = (const float*)d_in[6];
  const float* bnv  = (const float*)d_in[7];
  const float* bns  = (const float*)d_in[8];
  const float* bnc2 = (const float*)d_in[9];

  // ws layout: xq (1 MB) | idx (5 MB) | agg (16 MB)
  float4* xq = (float4*)d_ws;
  int* idx   = (int*)((char*)d_ws + (1 << 20));
  float* agg = (float*)((char*)d_ws + 6291456);
  float* out = (float*)d_out;

  prep_kernel<<<256, 256, 0, stream>>>(x, xq);
  knn_kernel<<<16384, 256, 0, stream>>>(xq, idx);
  lab_kernel<<<16384, 256, 0, stream>>>(xq, idx, Wk, Wv, Ws, bnk, bnv, bns, agg);
  conv2_kernel<<<256, 256, 0, stream>>>(agg, W2, b2, bnc2, out);
}